// Round 10
// baseline (242.015 us; speedup 1.0000x reference)
//
#include <hip/hip_runtime.h>
#include <hip/hip_bf16.h>
#include <stdint.h>
#include <math.h>

typedef __attribute__((ext_vector_type(8))) short bf16x8;
typedef __attribute__((ext_vector_type(4))) float f32x4;

#define D_K 256
#define JCHUNK 1024
#define SB 256              // superblock j-width (phase alternation unit)
#define NSB (JCHUNK / SB)   // 4
#define NST (SB / 16)       // 16 subtiles of 16 j per superblock

__device__ __forceinline__ unsigned short f2bf(float f) {
    unsigned u = __float_as_uint(f);
    u += 0x7fffu + ((u >> 16) & 1u);   // round-to-nearest-even
    return (unsigned short)(u >> 16);
}
__device__ __forceinline__ float bf2f(unsigned short u) {
    return __uint_as_float(((unsigned)u) << 16);
}

// ---------------- Kernel 1: row-normalize z -> bf16; zero partials ----------------
__global__ void normalize_k(const float* __restrict__ z,
                            unsigned short* __restrict__ zn,
                            float* __restrict__ part, int N) {
    int gid  = blockIdx.x * blockDim.x + threadIdx.x;
    if (gid < 5 * N) part[gid] = 0.f;      // stream-ordered before fused_k
    int gw   = gid >> 6;                   // one wave per row
    int lane = threadIdx.x & 63;
    if (gw >= N) return;
    float4 v = reinterpret_cast<const float4*>(z + (size_t)gw * D_K)[lane];
    float ss = v.x * v.x + v.y * v.y + v.z * v.z + v.w * v.w;
#pragma unroll
    for (int m = 32; m; m >>= 1) ss += __shfl_xor(ss, m);
    float sc = 1.0f / fmaxf(sqrtf(ss), 1e-8f);
    ushort4 o;
    o.x = f2bf(v.x * sc); o.y = f2bf(v.y * sc);
    o.z = f2bf(v.z * sc); o.w = f2bf(v.w * sc);
    reinterpret_cast<ushort4*>(zn + (size_t)gw * D_K)[lane] = o;
}

// ---------------- Kernel 2: pack zn into MFMA A-fragment order ----------------
// znp 16B-chunk index = jg*512 + ks*64 + lane, holding
// zn[jg*16 + (lane&15)][ks*32 + (lane>>4)*8 .. +8]  (jg = j>>4)
// => phase-1 fragment load becomes one coalesced 1KB global_load_dwordx4.
__global__ void pack_k(const unsigned short* __restrict__ zn,
                       unsigned short* __restrict__ znp, int N) {
    int jg = blockIdx.x;
    int t  = threadIdx.x;
    const unsigned short* src = zn + (size_t)jg * 16 * D_K;
    unsigned short* dst = znp + (size_t)jg * 4096;
#pragma unroll
    for (int h = 0; h < 2; ++h) {
        int p  = t + h * 256;          // 0..511
        int ks = p >> 6;
        int l  = p & 63;
        bf16x8 v = *reinterpret_cast<const bf16x8*>(
            src + (l & 15) * D_K + ks * 32 + (l >> 4) * 8);
        *reinterpret_cast<bf16x8*>(dst + (size_t)p * 8) = v;
    }
}

// ---------------- Kernel 3: two-phase fused kernel, ZERO barriers ----------------
// Each wave independently owns 16 i-rows x JCHUNK j. Per 256-j superblock:
//  phase 1: 16 subtiles of 16 j: A-frags = coalesced 1KB loads from L2-resident
//           znp straight to regs; B = persistent i-frags; MFMA -> sim;
//           exp->accden; park sim bf16 in wave-private LDS (8 KB).
//  phase 2: stream adj/tsim 1KB-contiguous per row (16-lane group per row),
//           dot vs parked sim.
// No __syncthreads / vmcnt asm anywhere: waves self-stagger across phases.
// part: [0,N) den | [N,2N) S1 | [2N,3N) A | [3N,4N) T1 | [4N,5N) T
__global__ __launch_bounds__(256, 4) void fused_k(
    const unsigned short* __restrict__ zn,
    const unsigned short* __restrict__ znp,
    const float* __restrict__ adj,
    const float* __restrict__ tsim,
    float* __restrict__ part, int N) {
    __shared__ alignas(128) char parkL[4][16 * 512];   // 4 waves x 8 KB bf16 park

    const float INV_T = 1.0f / 0.07f;
    const int NIB = N >> 6;                // 128
    int ib  = blockIdx.x & (NIB - 1);
    int jc  = blockIdx.x / NIB;            // 0..7
    int tid = threadIdx.x;
    int wid = tid >> 6, lane = tid & 63;
    int l15 = lane & 15, lhi = lane >> 4;
    int i0w = ib * 64 + wid * 16;
    int gi  = i0w + l15;                   // phase-1 output col = i-row
    int jb  = jc * JCHUNK;
    char* parkW = parkL[wid];

    // persistent B-operand fragments: zn row gi (32 VGPRs)
    bf16x8 bfr[8];
    {
        const bf16x8* bp = reinterpret_cast<const bf16x8*>(zn + (size_t)gi * D_K) + lhi;
#pragma unroll
        for (int ks = 0; ks < 8; ++ks) bfr[ks] = bp[ks * 4];
    }

    float accden = 0.f;                       // den partial for i-row gi
    float s1p[4] = {0.f, 0.f, 0.f, 0.f};      // phase-2 partials, row rg*4+lhi
    float app[4] = {0.f, 0.f, 0.f, 0.f};
    float t1p[4] = {0.f, 0.f, 0.f, 0.f};
    float ttp[4] = {0.f, 0.f, 0.f, 0.f};

    for (int sb = 0; sb < NSB; ++sb) {
        int jsb = jb + sb * SB;

        // ---------- phase 1: sim for 16 i x 256 j, all from registers/L2 ----------
        for (int st = 0; st < NST; ++st) {
            int j0 = jsb + st * 16;
            const bf16x8* ap = reinterpret_cast<const bf16x8*>(znp) +
                               ((size_t)(j0 >> 4) << 9) + lane;
            bf16x8 af[8];
#pragma unroll
            for (int ks = 0; ks < 8; ++ks) af[ks] = ap[ks * 64];  // 1KB coalesced each
            f32x4 acc = (f32x4){0.f, 0.f, 0.f, 0.f};
#pragma unroll
            for (int ks = 0; ks < 8; ++ks)
                acc = __builtin_amdgcn_mfma_f32_16x16x32_bf16(af[ks], bfr[ks], acc, 0, 0, 0);
            // lane holds sim[j' = j0+lhi*4+r][i' = gi]
            int jcol = st * 16 + lhi * 4;
            float sv[4];
#pragma unroll
            for (int r = 0; r < 4; ++r) {
                sv[r] = acc[r] * INV_T;
                accden += (gi == j0 + lhi * 4 + r) ? 0.f : __expf(sv[r]);
            }
            ushort4 pk;
            pk.x = f2bf(sv[0]); pk.y = f2bf(sv[1]);
            pk.z = f2bf(sv[2]); pk.w = f2bf(sv[3]);
            *reinterpret_cast<ushort4*>(
                parkW + l15 * 512 + ((jcol * 2) ^ ((l15 & 7) << 4))) = pk;
        }

        // wave-private DS ordering fence (write->read same wave)
        asm volatile("s_waitcnt lgkmcnt(0)" ::: "memory");
        __builtin_amdgcn_sched_barrier(0);

        // ---------- phase 2: stream adj/tsim, 1KB-contiguous per row ----------
#pragma unroll
        for (int rg = 0; rg < 4; ++rg) {
            int irow = rg * 4 + lhi;
            const float* ar = adj  + (size_t)(i0w + irow) * N + jsb + l15 * 8;
            const float* tr = tsim + (size_t)(i0w + irow) * N + jsb + l15 * 8;
            const char*  pr = parkW + irow * 512;
            int sx = (irow & 7) << 4;
#pragma unroll
            for (int q = 0; q < 2; ++q) {
                f32x4 a0 = __builtin_nontemporal_load(
                    reinterpret_cast<const f32x4*>(ar + q * 128));
                f32x4 a1 = __builtin_nontemporal_load(
                    reinterpret_cast<const f32x4*>(ar + q * 128 + 4));
                f32x4 t0 = __builtin_nontemporal_load(
                    reinterpret_cast<const f32x4*>(tr + q * 128));
                f32x4 t1 = __builtin_nontemporal_load(
                    reinterpret_cast<const f32x4*>(tr + q * 128 + 4));
                bf16x8 s8 = *reinterpret_cast<const bf16x8*>(
                    pr + ((l15 * 16 + q * 256) ^ sx));
                float s[8];
#pragma unroll
                for (int e = 0; e < 8; ++e) s[e] = bf2f((unsigned short)s8[e]);
                float s1 = s1p[rg], t1v = t1p[rg];
#pragma unroll
                for (int e = 0; e < 4; ++e) {
                    s1  = fmaf(a0[e], s[e], s1);
                    s1  = fmaf(a1[e], s[4 + e], s1);
                    t1v = fmaf(t0[e], s[e], t1v);
                    t1v = fmaf(t1[e], s[4 + e], t1v);
                }
                s1p[rg] = s1; t1p[rg] = t1v;
                app[rg] += (a0[0] + a0[1] + a0[2] + a0[3]) +
                           (a1[0] + a1[1] + a1[2] + a1[3]);
                ttp[rg] += (t0[0] + t0[1] + t0[2] + t0[3]) +
                           (t1[0] + t1[1] + t1[2] + t1[3]);
            }
        }
    }

    // ---------- final reductions + atomics ----------
    accden += __shfl_xor(accden, 16); accden += __shfl_xor(accden, 32);
    if (lhi == 0) atomicAdd(part + gi, accden);
#pragma unroll
    for (int rg = 0; rg < 4; ++rg) {
        float s = s1p[rg], a = app[rg], u = t1p[rg], w = ttp[rg];
#pragma unroll
        for (int m = 1; m < 16; m <<= 1) {
            s += __shfl_xor(s, m); a += __shfl_xor(a, m);
            u += __shfl_xor(u, m); w += __shfl_xor(w, m);
        }
        if (l15 == 0) {
            int gr = i0w + rg * 4 + lhi;
            atomicAdd(part + (size_t)N + gr, s);
            atomicAdd(part + (size_t)2 * N + gr, a);
            atomicAdd(part + (size_t)3 * N + gr, u);
            atomicAdd(part + (size_t)4 * N + gr, w);
        }
    }
}

// ---------------- Kernel 4: finalize scalar ----------------
__global__ void finalize_k(const float* __restrict__ part, float* __restrict__ out, int N) {
    const float* den = part;
    const float* s1  = part + (size_t)N;
    const float* aa  = part + (size_t)2 * N;
    const float* t1  = part + (size_t)3 * N;
    const float* tt  = part + (size_t)4 * N;
    float acc = 0.f;
    for (int i = threadIdx.x; i < N; i += blockDim.x) {
        float ld = logf(den[i] + 1e-8f);
        acc += -(s1[i] - ld * aa[i]) / (aa[i] + 1e-8f)
               - (t1[i] - ld * tt[i]) / (tt[i] + 1e-8f);
    }
#pragma unroll
    for (int m = 32; m; m >>= 1) acc += __shfl_xor(acc, m);
    __shared__ float red[16];
    if ((threadIdx.x & 63) == 0) red[threadIdx.x >> 6] = acc;
    __syncthreads();
    if (threadIdx.x == 0) {
        float tot = 0.f;
        int nw = blockDim.x >> 6;
        for (int w = 0; w < nw; ++w) tot += red[w];
        out[0] = tot / (float)N;
    }
}

extern "C" void kernel_launch(void* const* d_in, const int* in_sizes, int n_in,
                              void* d_out, int out_size, void* d_ws, size_t ws_size,
                              hipStream_t stream) {
    const float* z    = (const float*)d_in[0];
    const float* adj  = (const float*)d_in[1];
    const float* tsim = (const float*)d_in[2];

    int N = (int)(sqrt((double)in_sizes[1]) + 0.5);  // 8192

    unsigned short* zn  = (unsigned short*)d_ws;                                 // 4 MB
    unsigned short* znp = (unsigned short*)((char*)d_ws + (size_t)N * D_K * 2);  // 4 MB
    float* part = (float*)((char*)d_ws + (size_t)2 * N * D_K * 2);               // 5*N f32

    normalize_k<<<N / 4, 256, 0, stream>>>(z, zn, part, N);
    pack_k<<<N / 16, 256, 0, stream>>>(zn, znp, N);

    int nblocks = (N >> 6) * (N / JCHUNK);  // 128 * 8 = 1024
    fused_k<<<nblocks, 256, 0, stream>>>(zn, znp, adj, tsim, part, N);

    finalize_k<<<1, 1024, 0, stream>>>(part, (float*)d_out, N);
}

// Round 12
// 197.075 us; speedup vs baseline: 1.2280x; 1.2280x over previous
//
#include <hip/hip_runtime.h>
#include <hip/hip_bf16.h>
#include <stdint.h>
#include <math.h>

typedef __attribute__((ext_vector_type(8))) short bf16x8;
typedef __attribute__((ext_vector_type(4))) float f32x4;

#define D_K 256
#define JCHUNK 1024
#define BN 32
#define NT (JCHUNK / BN)    // 32 tiles per block

__device__ __forceinline__ unsigned short f2bf(float f) {
    unsigned u = __float_as_uint(f);
    u += 0x7fffu + ((u >> 16) & 1u);   // round-to-nearest-even
    return (unsigned short)(u >> 16);
}

__device__ __forceinline__ void gload_lds16(const void* g, void* l) {
    __builtin_amdgcn_global_load_lds(
        (const __attribute__((address_space(1))) void*)g,
        (__attribute__((address_space(3))) void*)l,
        16, 0, 0);
}

// ---------------- Kernel 1: row-normalize z -> bf16; zero partials ----------------
__global__ void normalize_k(const float* __restrict__ z,
                            unsigned short* __restrict__ zn,
                            float* __restrict__ part, int N) {
    int gid  = blockIdx.x * blockDim.x + threadIdx.x;
    if (gid < 5 * N) part[gid] = 0.f;      // stream-ordered before fused_k
    int gw   = gid >> 6;                   // one wave per row
    int lane = threadIdx.x & 63;
    if (gw >= N) return;
    float4 v = reinterpret_cast<const float4*>(z + (size_t)gw * D_K)[lane];
    float ss = v.x * v.x + v.y * v.y + v.z * v.z + v.w * v.w;
#pragma unroll
    for (int m = 32; m; m >>= 1) ss += __shfl_xor(ss, m);
    float sc = 1.0f / fmaxf(sqrtf(ss), 1e-8f);
    ushort4 o;
    o.x = f2bf(v.x * sc); o.y = f2bf(v.y * sc);
    o.z = f2bf(v.z * sc); o.w = f2bf(v.w * sc);
    reinterpret_cast<ushort4*>(zn + (size_t)gw * D_K)[lane] = o;
}

// Stage one 32-row x 256-d bf16 zn tile (16 KB) into LDS in [kslot][row][16B]
// layout (R6-proven: 0 bank conflicts). gload_lds dest linear; remap on source.
__device__ __forceinline__ void stage_zn(char* dst, const unsigned short* zn,
                                         int j0, int tid, int wid) {
#pragma unroll
    for (int it = 0; it < 4; ++it) {
        int li    = it * 4096 + tid * 16;
        int kslot = li >> 9;          // 0..31
        int row   = (li >> 4) & 31;   // 0..31
        const char* src = reinterpret_cast<const char*>(zn) +
                          ((size_t)(j0 + row) << 9) + (size_t)kslot * 16;
        gload_lds16(src, dst + it * 4096 + wid * 1024);
    }
}

// ---------------- Kernel 2: fused sim-GEMM + row reductions ----------------
// R6 structure, barrier-drain removed: counted vmcnt(4) + RAW s_barrier.
// CRITICAL: sched_barrier(0) pins the 4 gload_lds as the OLDEST outstanding
// VMEM ops (LLVM may otherwise interleave stream loads with stage loads,
// making the vmcnt(4) count unsound -> cross-wave LDS race -> R11's NaN).
// Per tile k: [stage(k+1)] PIN [streams(k+1)] [MFMA(k)] [consume streams(k)]
//             [vmcnt(4): stage landed, streams flying] [raw s_barrier]
// part: [0,N) den | [N,2N) S1 | [2N,3N) A | [3N,4N) T1 | [4N,5N) T
__global__ __launch_bounds__(256, 4) void fused_k(
    const unsigned short* __restrict__ zn,
    const float* __restrict__ adj,
    const float* __restrict__ tsim,
    float* __restrict__ part, int N) {
    __shared__ alignas(128) char L[2][BN * 512];   // 2 x 16 KB

    const float INV_T = 1.0f / 0.07f;
    const int NIB = N >> 6;
    int ib  = blockIdx.x & (NIB - 1);
    int jc  = blockIdx.x / NIB;
    int tid = threadIdx.x;
    int wid = tid >> 6, lane = tid & 63;
    int l15 = lane & 15, lhi = lane >> 4;
    int gi  = ib * 64 + wid * 16 + l15;     // this lane's i-row (output col)
    int jbase = jc * JCHUNK;

    // B-operand fragments: zn row gi, in registers for the whole sweep (32 VGPRs)
    bf16x8 bfr[8];
    {
        const bf16x8* bp = reinterpret_cast<const bf16x8*>(zn + (size_t)gi * D_K) + lhi;
#pragma unroll
        for (int ks = 0; ks < 8; ++ks) bfr[ks] = bp[ks * 4];
    }

    float accden = 0.f, accs1 = 0.f, acca = 0.f, acct1 = 0.f, acctt = 0.f;

    const float* abase = adj  + (size_t)gi * N + jbase + lhi * 4;
    const float* tbase = tsim + (size_t)gi * N + jbase + lhi * 4;

    // prologue: stage tile 0 (pinned oldest), then stream loads tile 0 (newest)
    stage_zn(L[0], zn, jbase, tid, wid);
    __builtin_amdgcn_sched_barrier(0);     // pin: stage before streams
    f32x4 av[2], tv[2];
#pragma unroll
    for (int t = 0; t < 2; ++t) {
        av[t] = __builtin_nontemporal_load(reinterpret_cast<const f32x4*>(abase + t * 16));
        tv[t] = __builtin_nontemporal_load(reinterpret_cast<const f32x4*>(tbase + t * 16));
    }
    asm volatile("s_waitcnt vmcnt(4)" ::: "memory");   // stage(0) done; streams(0) flying
    __builtin_amdgcn_s_barrier();

    for (int jt = 0; jt < NT; ++jt) {
        const char* buf = L[jt & 1];

        // 1) issue next tile's staging (pinned oldest) + stream loads (newest)
        f32x4 nav[2], ntv[2];
        if (jt + 1 < NT) {
            stage_zn(L[(jt & 1) ^ 1], zn, jbase + (jt + 1) * BN, tid, wid);
            __builtin_amdgcn_sched_barrier(0);   // pin: stage before streams
            const float* an = abase + (jt + 1) * BN;
            const float* tn = tbase + (jt + 1) * BN;
#pragma unroll
            for (int t = 0; t < 2; ++t) {
                nav[t] = __builtin_nontemporal_load(reinterpret_cast<const f32x4*>(an + t * 16));
                ntv[t] = __builtin_nontemporal_load(reinterpret_cast<const f32x4*>(tn + t * 16));
            }
        }

        // 2) MFMA tile k from LDS ([kslot][row][16B]: conflict-free reads)
        f32x4 acc[2] = {(f32x4){0.f,0.f,0.f,0.f}, (f32x4){0.f,0.f,0.f,0.f}};
#pragma unroll
        for (int ks = 0; ks < 8; ++ks) {
#pragma unroll
            for (int t = 0; t < 2; ++t) {
                int boff = (ks << 11) + (lhi << 9) + (t << 8) + (l15 << 4);
                bf16x8 aj = *reinterpret_cast<const bf16x8*>(buf + boff);
                acc[t] = __builtin_amdgcn_mfma_f32_16x16x32_bf16(aj, bfr[ks], acc[t], 0, 0, 0);
            }
        }

        // 3) epilogue: consume streams(k) (issued one tile ago; compiler emits
        //    its own counted wait for exactly these, modeling gload_lds too)
        int j0 = jbase + jt * BN;
#pragma unroll
        for (int t = 0; t < 2; ++t) {
            int gj0 = j0 + t * 16 + lhi * 4;
#pragma unroll
            for (int r = 0; r < 4; ++r) {
                float sim = acc[t][r] * INV_T;
                float e   = (gi == gj0 + r) ? 0.f : __expf(sim);
                float a   = av[t][r];
                float w   = tv[t][r];
                accden += e;
                accs1 = fmaf(a, sim, accs1);  acca  += a;
                acct1 = fmaf(w, sim, acct1);  acctt += w;
            }
        }
        if (jt + 1 < NT) {
#pragma unroll
            for (int t = 0; t < 2; ++t) { av[t] = nav[t]; tv[t] = ntv[t]; }
        }

        // 4) counted wait: stage(k+1) (oldest 4) landed; streams(k+1) STAY in
        //    flight. RAW barrier (no implicit vmcnt(0) drain).
        asm volatile("s_waitcnt vmcnt(4)" ::: "memory");
        __builtin_amdgcn_s_barrier();
    }

    // lanes lhi=0..3 share gi: reduce, one atomic per row per counter
    accden += __shfl_xor(accden, 16); accden += __shfl_xor(accden, 32);
    accs1  += __shfl_xor(accs1, 16);  accs1  += __shfl_xor(accs1, 32);
    acca   += __shfl_xor(acca, 16);   acca   += __shfl_xor(acca, 32);
    acct1  += __shfl_xor(acct1, 16);  acct1  += __shfl_xor(acct1, 32);
    acctt  += __shfl_xor(acctt, 16);  acctt  += __shfl_xor(acctt, 32);
    if (lhi == 0) {
        atomicAdd(part + gi, accden);
        atomicAdd(part + (size_t)N + gi, accs1);
        atomicAdd(part + (size_t)2 * N + gi, acca);
        atomicAdd(part + (size_t)3 * N + gi, acct1);
        atomicAdd(part + (size_t)4 * N + gi, acctt);
    }
}

// ---------------- Kernel 3: finalize scalar ----------------
__global__ void finalize_k(const float* __restrict__ part, float* __restrict__ out, int N) {
    const float* den = part;
    const float* s1  = part + (size_t)N;
    const float* aa  = part + (size_t)2 * N;
    const float* t1  = part + (size_t)3 * N;
    const float* tt  = part + (size_t)4 * N;
    float acc = 0.f;
    for (int i = threadIdx.x; i < N; i += blockDim.x) {
        float ld = logf(den[i] + 1e-8f);
        acc += -(s1[i] - ld * aa[i]) / (aa[i] + 1e-8f)
               - (t1[i] - ld * tt[i]) / (tt[i] + 1e-8f);
    }
#pragma unroll
    for (int m = 32; m; m >>= 1) acc += __shfl_xor(acc, m);
    __shared__ float red[16];
    if ((threadIdx.x & 63) == 0) red[threadIdx.x >> 6] = acc;
    __syncthreads();
    if (threadIdx.x == 0) {
        float tot = 0.f;
        int nw = blockDim.x >> 6;
        for (int w = 0; w < nw; ++w) tot += red[w];
        out[0] = tot / (float)N;
    }
}

extern "C" void kernel_launch(void* const* d_in, const int* in_sizes, int n_in,
                              void* d_out, int out_size, void* d_ws, size_t ws_size,
                              hipStream_t stream) {
    const float* z    = (const float*)d_in[0];
    const float* adj  = (const float*)d_in[1];
    const float* tsim = (const float*)d_in[2];

    int N = (int)(sqrt((double)in_sizes[1]) + 0.5);  // 8192

    unsigned short* zn = (unsigned short*)d_ws;                   // 4 MB
    float* part = (float*)((char*)d_ws + (size_t)N * D_K * 2);    // 5*N f32

    normalize_k<<<N / 4, 256, 0, stream>>>(z, zn, part, N);

    int nblocks = (N >> 6) * (N / JCHUNK);  // 128 * 8 = 1024
    fused_k<<<nblocks, 256, 0, stream>>>(zn, adj, tsim, part, N);

    finalize_k<<<1, 1024, 0, stream>>>(part, (float*)d_out, N);
}